// Round 6
// baseline (1309.660 us; speedup 1.0000x reference)
//
#include <hip/hip_runtime.h>
#include <hip/hip_bf16.h>
#include <math.h>

#define SPX 1024
#define HW 16384

typedef short short8 __attribute__((ext_vector_type(8)));
typedef short short4v __attribute__((ext_vector_type(4)));
typedef float f32x4 __attribute__((ext_vector_type(4)));

__device__ inline short f2bf(float v){ union{ __hip_bfloat16 h; short s; } u; u.h = __float2bfloat16(v); return u.s; }
__device__ inline float bf2f(short s){ union{ __hip_bfloat16 h; short t; } u; u.t = s; return __bfloat162float(u.h); }

#define GLL(gp, lp) __builtin_amdgcn_global_load_lds( \
    (const __attribute__((address_space(1))) void*)(gp), \
    (__attribute__((address_space(3))) void*)(lp), 16, 0, 0)

// ---------------- mega prep: conv weights, THWC, LS pooling, all weight transposes ----------------
__global__ __launch_bounds__(256) void megaprep_k(
    const float* __restrict__ T1, const float* __restrict__ T2,
    const float* __restrict__ cwin, const float* __restrict__ cw,
    const float* __restrict__ qkvW, const float* __restrict__ outW,
    const float* __restrict__ ff1W, const float* __restrict__ ff2W,
    const float* __restrict__ fcW, const float* __restrict__ fc0W,
    short* __restrict__ wt0, short* __restrict__ wtl, short* __restrict__ zbuf,
    short* __restrict__ thwc, float* __restrict__ LSb,
    short* __restrict__ qkvWT, short* __restrict__ outWT,
    short* __restrict__ ff1T, short* __restrict__ ff2T,
    short* __restrict__ fcT, short* __restrict__ fc0WT)
{
    __shared__ float tile[32][33];
    int bid = blockIdx.x;
    int tid = threadIdx.x;
    if (bid < 27072) {
        long long idx = (long long)bid * 256 + tid;
        if (idx < 64) zbuf[idx] = 0;
        const long long n0 = 2LL * 256 * 2016;
        if (idx < n0) {
            int br = (int)(idx / (256 * 2016)); int rem = (int)(idx % (256 * 2016));
            int co = rem / 2016; int k = rem % 2016;
            int tap = k / 224, ci = k % 224;
            wt0[idx] = f2bf(cwin[((size_t)(br * 256 + co) * 224 + ci) * 9 + tap]);
        } else {
            long long i2 = idx - n0;
            if (i2 < 10LL * 256 * 2304) {
                int l = (int)(i2 / (256 * 2304)); int rem = (int)(i2 % (256 * 2304));
                int co = rem / 2304; int k = rem % 2304;
                int tap = k / 256, ci = k % 256;
                wtl[i2] = f2bf(cw[((size_t)(l * 256 + co) * 256 + ci) * 9 + tap]);
            }
        }
        return;
    }
    bid -= 27072;
    if (bid < 28672) {
        long long idx = (long long)bid * 256 + tid;
        int br = (int)(idx / 3670016LL); int rem = (int)(idx % 3670016LL);
        int p = rem / 224, c = rem % 224;
        const float* src = br ? T2 : T1;
        thwc[idx] = f2bf(src[(size_t)c * HW + p]);
        return;
    }
    bid -= 28672;
    if (bid < 1792) {
        int idx = bid * 256 + tid;
        int z = idx / 229376; int rem = idx % 229376;
        int c = rem >> 10, s = rem & 1023;
        const float* src = z ? T2 : T1;
        const float* p = src + (size_t)c * HW + s;
        float acc = 0.f;
#pragma unroll
        for (int j = 0; j < 16; ++j) acc += p[j * 1024];
        LSb[(size_t)z * 229376 + (size_t)s * 224 + c] = acc * (1.f / 16.f);
        return;
    }
    bid -= 1792;
    const float* src; short* dst; int K, N, nx;
    if (bid < 4608)                        { src = qkvW; dst = qkvWT; K = 256; N = 1536; nx = 48; }
    else { bid -= 4608; if (bid < 1536)    { src = outW; dst = outWT; K = 512; N = 256;  nx = 8; }
    else { bid -= 1536; if (bid < 1536)    { src = ff1W; dst = ff1T;  K = 256; N = 512;  nx = 16; }
    else { bid -= 1536; if (bid < 1536)    { src = ff2W; dst = ff2T;  K = 512; N = 256;  nx = 8; }
    else { bid -= 1536; if (bid < 1280)    { src = fcW;  dst = fcT;   K = 512; N = 256;  nx = 8; }
    else { bid -= 1280;                      src = fc0W; dst = fc0WT; K = 480; N = 256;  nx = 8; } } } } }
    int per = nx * (K >> 5);
    int b = bid / per, rem = bid % per;
    int n0 = (rem % nx) * 32, k0 = (rem / nx) * 32;
    const float* s = src + (size_t)b * K * N;
    short* d = dst + (size_t)b * K * N;
    int r = tid >> 3, c4 = (tid & 7) * 4;
    float4 v = *(const float4*)(s + (size_t)(k0 + r) * N + n0 + c4);
    tile[r][c4 + 0] = v.x; tile[r][c4 + 1] = v.y; tile[r][c4 + 2] = v.z; tile[r][c4 + 3] = v.w;
    __syncthreads();
    short4v o;
#pragma unroll
    for (int i = 0; i < 4; ++i) o[i] = f2bf(tile[c4 + i][r]);
    *(short4v*)(d + (size_t)(n0 + r) * K + k0 + c4) = o;
}

// ---------------- conv v4: A halo in LDS (1 stage/chunk), B register-prefetched from L2 ----------
// 1D grid 512, XCD-banded: xcd=id&7 -> {branch, 32-row band}; t=id>>3 -> {y, co-half}.
// Per 32-ci chunk: stage 3x130 halo A once (2 barriers), then 9 taps of pure
// ds_read(A) + reg-B MFMA with B(tap+1) global-prefetched during MFMA(tap).
__global__ __launch_bounds__(256, 3) void conv_mfma_k(
    const short* __restrict__ inB, long long inStride,
    const short* __restrict__ wtB, long long wtStride,
    const float* __restrict__ biasB, long long biasStride,
    short* __restrict__ outB, long long outStride,
    const short* __restrict__ zbuf, int Cin)
{
    __shared__ short Ah[3 * 4160];    // 3 dy x 130 rows x 32 ci (rows 0/129 zero guards)
    int id = blockIdx.x;
    int x7 = id & 7, t = id >> 3;
    int br = x7 & 1;
    int y = (x7 >> 1) * 32 + (t >> 1);
    int co0 = (t & 1) * 128;
    const short* in = inB + (size_t)br * inStride;
    const short* wt = wtB + (size_t)br * wtStride;
    const float* bias = biasB + (size_t)br * biasStride;
    short* out = outB + (size_t)br * outStride;
    int tid = threadIdx.x;
    int lane = tid & 63, w = tid >> 6;
    int wm = w >> 1, wn = w & 1;
    int lrow = lane >> 2, lsub = (lane & 3) * 8;
    int mrow = lane & 15, quad = lane >> 4, kg = quad * 8;
    int Kw = 9 * Cin;
    if (tid < 96) {
        int dy = tid >> 5, ci = tid & 31;
        Ah[dy * 4160 + ci] = 0;
        Ah[dy * 4160 + 129 * 32 + ci] = 0;
    }
    f32x4 acc[4][4];
#pragma unroll
    for (int i = 0; i < 4; ++i)
#pragma unroll
        for (int j = 0; j < 4; ++j) acc[i][j] = (f32x4){0.f, 0.f, 0.f, 0.f};

    const short* wbase[4];
#pragma unroll
    for (int j = 0; j < 4; ++j)
        wbase[j] = wt + (size_t)(co0 + wn * 64 + j * 16 + mrow) * Kw + kg;

    auto stageA = [&](int cc) {
        int c8 = cc * 32;
#pragma unroll
        for (int g = 0; g < 6; ++g) {
            int idg = g * 4 + w;
            int dy = idg >> 3, grp = idg & 7;
            int gy = y + dy - 1;
            const short* gp = ((unsigned)gy < 128u)
                ? in + ((size_t)(gy * 128 + grp * 16 + lrow) * Cin + c8 + lsub)
                : zbuf + lsub;
            GLL(gp, Ah + dy * 4160 + (1 + grp * 16) * 32);
        }
    };

    short8 Bcur[4], Bnxt[4];
#pragma unroll
    for (int j = 0; j < 4; ++j) Bcur[j] = *(const short8*)(wbase[j]);   // (cc=0, tap=0)
    stageA(0);
    __syncthreads();
    int NC = Cin >> 5;
    for (int cc = 0; cc < NC; ++cc) {
        int cbase = cc * 32;
#pragma unroll
        for (int tap = 0; tap < 9; ++tap) {
            if (tap < 8) {
#pragma unroll
                for (int j = 0; j < 4; ++j)
                    Bnxt[j] = *(const short8*)(wbase[j] + (tap + 1) * Cin + cbase);
            } else if (cc + 1 < NC) {
#pragma unroll
                for (int j = 0; j < 4; ++j)
                    Bnxt[j] = *(const short8*)(wbase[j] + cbase + 32);
            }
            const short* Ap = Ah + (tap / 3) * 4160 + (tap % 3) * 32;
            short8 af[4];
#pragma unroll
            for (int i = 0; i < 4; ++i)
                af[i] = *(const short8*)(Ap + (wm * 64 + i * 16 + mrow) * 32 + kg);
#pragma unroll
            for (int i = 0; i < 4; ++i)
#pragma unroll
                for (int j = 0; j < 4; ++j)
                    acc[i][j] = __builtin_amdgcn_mfma_f32_16x16x32_bf16(af[i], Bcur[j], acc[i][j], 0, 0, 0);
#pragma unroll
            for (int j = 0; j < 4; ++j) Bcur[j] = Bnxt[j];
        }
        if (cc + 1 < NC) {
            __syncthreads();
            stageA(cc + 1);
            __syncthreads();
        }
    }
    int ln15 = lane & 15;
    float bj[4];
#pragma unroll
    for (int j = 0; j < 4; ++j) bj[j] = bias[co0 + wn * 64 + j * 16 + ln15];
#pragma unroll
    for (int i = 0; i < 4; ++i) {
#pragma unroll
        for (int r = 0; r < 4; ++r) {
            int px = wm * 64 + i * 16 + quad * 4 + r;
            size_t po = ((size_t)y * 128 + px) * 256 + co0 + wn * 64 + ln15;
#pragma unroll
            for (int j = 0; j < 4; ++j)
                out[po + j * 16] = f2bf(acc[i][j][r] + bj[j]);
        }
    }
}

// ---------------- bf16 MFMA GEMM, 64x64 tile, BK=32, double-buffered ----------------
__global__ __launch_bounds__(256) void gemm64_k(
    const short* __restrict__ A, long long sA, int lda,
    const short* __restrict__ Bt, long long sB, int K,
    float* Cf, long long sCf, short* Cb, long long sCb, int ldc,
    const float* __restrict__ bias, long long sBias,
    const float* addm, long long sAdd, int ldadd, int act)
{
    __shared__ short Asm[2][2048];
    __shared__ short Bsm[2][2048];
    int z = blockIdx.z;
    const short* Ap = A + (size_t)z * sA;
    const short* Bp = Bt + (size_t)z * sB;
    const float* biasp = bias ? bias + (size_t)z * sBias : nullptr;
    const float* addp = addm ? addm + (size_t)z * sAdd : nullptr;
    int bn = blockIdx.x * 64, bm = blockIdx.y * 64;
    int tid = threadIdx.x;
    int lane = tid & 63, w = tid >> 6;
    int wm = w >> 1, wn = w & 1;
    int rr = tid >> 2, lsub = (tid & 3) * 8;
    f32x4 acc[2][2];
#pragma unroll
    for (int i = 0; i < 2; ++i)
#pragma unroll
        for (int j = 0; j < 2; ++j) acc[i][j] = (f32x4){0.f, 0.f, 0.f, 0.f};

    auto stage = [&](int k0, int p) {
        GLL(Ap + (size_t)(bm + rr) * lda + k0 + lsub, Asm[p] + (w * 16) * 32);
        GLL(Bp + (size_t)(bn + rr) * K + k0 + lsub, Bsm[p] + (w * 16) * 32);
    };
    stage(0, 0);
    __syncthreads();
    int p = 0;
    int mrow = lane & 15, kg = (lane >> 4) * 8;
    for (int k0 = 0; k0 < K; k0 += 32) {
        if (k0 + 32 < K) stage(k0 + 32, p ^ 1);
        short8 af[2], bfr[2];
#pragma unroll
        for (int i = 0; i < 2; ++i)
            af[i] = *(const short8*)(Asm[p] + (wm * 32 + i * 16 + mrow) * 32 + kg);
#pragma unroll
        for (int j = 0; j < 2; ++j)
            bfr[j] = *(const short8*)(Bsm[p] + (wn * 32 + j * 16 + mrow) * 32 + kg);
#pragma unroll
        for (int i = 0; i < 2; ++i)
#pragma unroll
            for (int j = 0; j < 2; ++j)
                acc[i][j] = __builtin_amdgcn_mfma_f32_16x16x32_bf16(af[i], bfr[j], acc[i][j], 0, 0, 0);
        __syncthreads();
        p ^= 1;
    }
    int ln15 = lane & 15, quad = lane >> 4;
    float* Cfp = Cf ? Cf + (size_t)z * sCf : nullptr;
    short* Cbp = Cb ? Cb + (size_t)z * sCb : nullptr;
#pragma unroll
    for (int i = 0; i < 2; ++i) {
#pragma unroll
        for (int r = 0; r < 4; ++r) {
            int row = bm + wm * 32 + i * 16 + quad * 4 + r;
            long long ro = (long long)row * ldc;
#pragma unroll
            for (int j = 0; j < 2; ++j) {
                int col = bn + wn * 32 + j * 16 + ln15;
                float v = acc[i][j][r];
                if (biasp) v += biasp[col];
                if (addp) v += addp[(long long)row * ldadd + col];
                if (act == 1) v = fmaxf(v, 0.f);
                else if (act == 2) v = 0.5f * v * (1.f + erff(v * 0.70710678118f));
                if (Cfp) Cfp[ro + col] = v;
                if (Cbp) Cbp[ro + col] = f2bf(v);
            }
        }
    }
}

// ---------------- full-row GEMM (N=256) + bias + add + LayerNorm fused epilogue ----------------
__global__ __launch_bounds__(256) void gemm_ln_k(
    const short* __restrict__ A, long long sA, int lda,
    const short* __restrict__ Bt, long long sB, int K,
    const float* __restrict__ bias, long long sBias,
    const float* __restrict__ addm, long long sAdd,
    const float* __restrict__ g, const float* __restrict__ b,
    float* __restrict__ xout, long long sX, short* __restrict__ hout, long long sH)
{
    __shared__ short As[2][512];
    __shared__ short Bsm[2][8192];
    __shared__ float redS[16][4], redQ[16][4];
    int z = blockIdx.y;
    int bm = blockIdx.x * 16;
    const short* Ap = A + (size_t)z * sA;
    const short* Bp = Bt + (size_t)z * sB;
    const float* biasp = bias + (size_t)z * sBias;
    const float* addp = addm + (size_t)z * sAdd;
    const float* gp = g + (size_t)z * 256;
    const float* bp = b + (size_t)z * 256;
    float* xo = xout + (size_t)z * sX;
    short* ho = hout + (size_t)z * sH;
    int tid = threadIdx.x;
    int lane = tid & 63, w = tid >> 6;
    int lrow = lane >> 2, lsub = (lane & 3) * 8;
    int mrow = lane & 15, quad = lane >> 4, kg = quad * 8;
    f32x4 acc[4];
#pragma unroll
    for (int j = 0; j < 4; ++j) acc[j] = (f32x4){0.f, 0.f, 0.f, 0.f};

    auto stage = [&](int k0, int p) {
        if (w == 0) GLL(Ap + (size_t)(bm + lrow) * lda + k0 + lsub, As[p]);
#pragma unroll
        for (int s = 0; s < 4; ++s) {
            int r0 = (w * 4 + s) * 16;
            GLL(Bp + (size_t)(r0 + lrow) * K + k0 + lsub, Bsm[p] + r0 * 32);
        }
    };
    stage(0, 0);
    __syncthreads();
    int NK = K >> 5, p = 0;
    for (int kk = 0; kk < NK; ++kk) {
        if (kk + 1 < NK) stage((kk + 1) * 32, p ^ 1);
        short8 af = *(const short8*)(As[p] + mrow * 32 + kg);
#pragma unroll
        for (int j = 0; j < 4; ++j) {
            short8 bfr = *(const short8*)(Bsm[p] + (w * 64 + j * 16 + mrow) * 32 + kg);
            acc[j] = __builtin_amdgcn_mfma_f32_16x16x32_bf16(af, bfr, acc[j], 0, 0, 0);
        }
        __syncthreads();
        p ^= 1;
    }
    float v[4][4], s4[4], q4[4];
#pragma unroll
    for (int r = 0; r < 4; ++r) { s4[r] = 0.f; q4[r] = 0.f; }
#pragma unroll
    for (int j = 0; j < 4; ++j) {
        int col = w * 64 + j * 16 + mrow;
        float bb = biasp[col];
#pragma unroll
        for (int r = 0; r < 4; ++r) {
            int row = bm + quad * 4 + r;
            float val = acc[j][r] + bb + addp[(size_t)row * 256 + col];
            v[j][r] = val;
            s4[r] += val;
            q4[r] += val * val;
        }
    }
#pragma unroll
    for (int r = 0; r < 4; ++r) {
#pragma unroll
        for (int msk = 1; msk < 16; msk <<= 1) {
            s4[r] += __shfl_xor(s4[r], msk);
            q4[r] += __shfl_xor(q4[r], msk);
        }
    }
    if (mrow == 0) {
#pragma unroll
        for (int r = 0; r < 4; ++r) {
            redS[quad * 4 + r][w] = s4[r];
            redQ[quad * 4 + r][w] = q4[r];
        }
    }
    __syncthreads();
#pragma unroll
    for (int r = 0; r < 4; ++r) {
        int r16 = quad * 4 + r;
        float S = redS[r16][0] + redS[r16][1] + redS[r16][2] + redS[r16][3];
        float Q = redQ[r16][0] + redQ[r16][1] + redQ[r16][2] + redQ[r16][3];
        float m = S * (1.f / 256.f);
        float var = Q * (1.f / 256.f) - m * m;
        float rs = rsqrtf(var + 1e-5f);
        size_t ro = (size_t)(bm + r16) * 256;
#pragma unroll
        for (int j = 0; j < 4; ++j) {
            int col = w * 64 + j * 16 + mrow;
            xo[ro + col] = v[j][r];
            ho[ro + col] = f2bf((v[j][r] - m) * rs * gp[col] + bp[col]);
        }
    }
}

// ---------------- fused flash attention: per block (64 Q-rows, head, branch) ----------------
__global__ __launch_bounds__(256) void flash_k(const short* __restrict__ qkv, const float* __restrict__ Abias,
                                               short* __restrict__ obuf)
{
    __shared__ short Qs[64 * 72];
    __shared__ short Ks[128 * 72];
    __shared__ short Vt[64 * 136];
    __shared__ short Ps[64 * 136];
    int q0 = blockIdx.x * 64, h = blockIdx.y, br = blockIdx.z;
    const short* qb = qkv + (size_t)br * 1572864;
    int tid = threadIdx.x;
    int lane = tid & 63, w = tid >> 6;
    int ln15 = lane & 15, quad = lane >> 4;
    {
        int row = tid & 63, c0 = (tid >> 6) * 16;
        const short* src = qb + (size_t)(q0 + row) * 1536 + h * 64 + c0;
        *(short8*)(Qs + row * 72 + c0) = *(const short8*)src;
        *(short8*)(Qs + row * 72 + c0 + 8) = *(const short8*)(src + 8);
    }
    f32x4 Oc[4];
    float mrow[4], lsum[4];
#pragma unroll
    for (int i = 0; i < 4; ++i) { Oc[i] = (f32x4){0.f, 0.f, 0.f, 0.f}; mrow[i] = -1e30f; lsum[i] = 0.f; }

    for (int j = 0; j < 8; ++j) {
        int k0 = j * 128;
        {
            int row = tid & 127, half = tid >> 7;
            const short* ks = qb + (size_t)(k0 + row) * 1536 + 512 + h * 64 + half * 32;
#pragma unroll
            for (int g = 0; g < 4; ++g)
                *(short8*)(Ks + row * 72 + half * 32 + g * 8) = *(const short8*)(ks + g * 8);
            const short* vs = qb + (size_t)(k0 + row) * 1536 + 1024 + h * 64 + half * 32;
#pragma unroll
            for (int g = 0; g < 4; ++g) {
                short8 vv = *(const short8*)(vs + g * 8);
#pragma unroll
                for (int e = 0; e < 8; ++e)
                    Vt[(half * 32 + g * 8 + e) * 136 + row] = vv[e];
            }
        }
        __syncthreads();
        short8 aq[2];
#pragma unroll
        for (int g = 0; g < 2; ++g)
            aq[g] = *(const short8*)(Qs + (w * 16 + ln15) * 72 + g * 32 + quad * 8);
        f32x4 Sf[8];
#pragma unroll
        for (int nf = 0; nf < 8; ++nf) Sf[nf] = (f32x4){0.f, 0.f, 0.f, 0.f};
#pragma unroll
        for (int nf = 0; nf < 8; ++nf)
#pragma unroll
            for (int g = 0; g < 2; ++g) {
                short8 bk = *(const short8*)(Ks + (nf * 16 + ln15) * 72 + g * 32 + quad * 8);
                Sf[nf] = __builtin_amdgcn_mfma_f32_16x16x32_bf16(aq[g], bk, Sf[nf], 0, 0, 0);
            }
        float rm[4] = {-1e30f, -1e30f, -1e30f, -1e30f};
#pragma unroll
        for (int nf = 0; nf < 8; ++nf)
#pragma unroll
            for (int r = 0; r < 4; ++r) {
                float v = Sf[nf][r] * 0.125f +
                          Abias[(size_t)(q0 + w * 16 + quad * 4 + r) * 1024 + k0 + nf * 16 + ln15];
                Sf[nf][r] = v;
                rm[r] = fmaxf(rm[r], v);
            }
#pragma unroll
        for (int r = 0; r < 4; ++r)
#pragma unroll
            for (int msk = 1; msk < 16; msk <<= 1)
                rm[r] = fmaxf(rm[r], __shfl_xor(rm[r], msk));
        float alpha[4], rs[4];
#pragma unroll
        for (int r = 0; r < 4; ++r) {
            float mnew = fmaxf(mrow[r], rm[r]);
            alpha[r] = __expf(mrow[r] - mnew);
            mrow[r] = mnew;
            rs[r] = 0.f;
        }
#pragma unroll
        for (int nf = 0; nf < 8; ++nf)
#pragma unroll
            for (int r = 0; r < 4; ++r) {
                float pv = __expf(Sf[nf][r] - mrow[r]);
                Sf[nf][r] = pv;
                rs[r] += pv;
            }
#pragma unroll
        for (int r = 0; r < 4; ++r) {
#pragma unroll
            for (int msk = 1; msk < 16; msk <<= 1)
                rs[r] += __shfl_xor(rs[r], msk);
            lsum[r] = lsum[r] * alpha[r] + rs[r];
        }
#pragma unroll
        for (int nf = 0; nf < 4; ++nf)
#pragma unroll
            for (int r = 0; r < 4; ++r) Oc[nf][r] *= alpha[r];
#pragma unroll
        for (int nf = 0; nf < 8; ++nf)
#pragma unroll
            for (int r = 0; r < 4; ++r)
                Ps[(w * 16 + quad * 4 + r) * 136 + nf * 16 + ln15] = f2bf(Sf[nf][r]);
        __syncthreads();
#pragma unroll
        for (int g = 0; g < 4; ++g) {
            short8 ap = *(const short8*)(Ps + (w * 16 + ln15) * 136 + g * 32 + quad * 8);
#pragma unroll
            for (int nf = 0; nf < 4; ++nf) {
                short8 bv = *(const short8*)(Vt + (nf * 16 + ln15) * 136 + g * 32 + quad * 8);
                Oc[nf] = __builtin_amdgcn_mfma_f32_16x16x32_bf16(ap, bv, Oc[nf], 0, 0, 0);
            }
        }
        __syncthreads();
    }
#pragma unroll
    for (int nf = 0; nf < 4; ++nf)
#pragma unroll
        for (int r = 0; r < 4; ++r) {
            int row = q0 + w * 16 + quad * 4 + r;
            obuf[(size_t)br * 524288 + (size_t)row * 512 + h * 64 + nf * 16 + ln15] =
                f2bf(Oc[nf][r] / lsum[r]);
        }
}

// ---------------- fused pool(conv,256) + concat(b,cb) + relu -> bf16 catr ----------------
__global__ __launch_bounds__(256) void poolcat_k(const short* __restrict__ conv, long long convZ,
                                                 const float* __restrict__ bsrc, long long bZ, int cb,
                                                 short* __restrict__ catr, long long catZ)
{
    int row = blockIdx.x, z = blockIdx.y, tid = threadIdx.x;
    const short* p = conv + (size_t)z * convZ + (size_t)row * 256 + tid;
    float acc = 0.f;
#pragma unroll
    for (int j = 0; j < 16; ++j) acc += bf2f(p[(size_t)j * 262144]);
    int n = 256 + cb;
    short* op = catr + (size_t)z * catZ + (size_t)row * n;
    op[tid] = f2bf(fmaxf(acc * (1.f / 16.f), 0.f));
    if (tid < cb)
        op[256 + tid] = f2bf(fmaxf(bsrc[(size_t)z * bZ + (size_t)row * cb + tid], 0.f));
}

// ---------------- head GEMM with fused |x0-x1| A-staging (fp32, 64x64 tiles) ----------------
__global__ __launch_bounds__(256) void head1_k(const float* __restrict__ x0, const float* __restrict__ x1,
                                               const float* __restrict__ B, float* __restrict__ C,
                                               const float* __restrict__ bias)
{
    __shared__ __align__(16) float As[16][68];
    __shared__ __align__(16) float Bs[16][68];
    const int K = 256, lda = 256, ldb = 128, ldc = 128;
    int bn = blockIdx.x * 64, bm = blockIdx.y * 64;
    int tid = threadIdx.x;
    int tx = tid & 15, ty = tid >> 4;
    float acc[4][4];
#pragma unroll
    for (int r = 0; r < 4; ++r)
#pragma unroll
        for (int c = 0; c < 4; ++c) acc[r][c] = 0.f;
    int mmA = tid >> 2, kqA = (tid & 3) * 4;
    int kkB = tid >> 4, nqB = (tid & 15) * 4;
    for (int k0 = 0; k0 < K; k0 += 16) {
        float4 a0 = *(const float4*)(x0 + (long long)(bm + mmA) * lda + k0 + kqA);
        float4 a1 = *(const float4*)(x1 + (long long)(bm + mmA) * lda + k0 + kqA);
        As[kqA + 0][mmA] = fabsf(a0.x - a1.x); As[kqA + 1][mmA] = fabsf(a0.y - a1.y);
        As[kqA + 2][mmA] = fabsf(a0.z - a1.z); As[kqA + 3][mmA] = fabsf(a0.w - a1.w);
        *(float4*)&Bs[kkB][nqB] = *(const float4*)(B + (long long)(k0 + kkB) * ldb + bn + nqB);
        __syncthreads();
#pragma unroll
        for (int kk = 0; kk < 16; ++kk) {
            float4 a4 = *(const float4*)&As[kk][ty * 4];
            float4 b4 = *(const float4*)&Bs[kk][tx * 4];
            float ar[4] = {a4.x, a4.y, a4.z, a4.w};
            float br[4] = {b4.x, b4.y, b4.z, b4.w};
#pragma unroll
            for (int r = 0; r < 4; ++r)
#pragma unroll
                for (int c = 0; c < 4; ++c) acc[r][c] += ar[r] * br[c];
        }
        __syncthreads();
    }
#pragma unroll
    for (int r = 0; r < 4; ++r) {
        int row = bm + ty * 4 + r;
#pragma unroll
        for (int c = 0; c < 4; ++c) {
            int col = bn + tx * 4 + c;
            C[(long long)row * ldc + col] = fmaxf(acc[r][c] + bias[col], 0.f);
        }
    }
}

__global__ __launch_bounds__(256) void head2_k(const float* __restrict__ hh, const float* __restrict__ W2,
                                               const float* __restrict__ b2, float* __restrict__ out)
{
    int s = blockIdx.x * 256 + threadIdx.x;
    if (s >= SPX) return;
    float l0 = b2[0], l1 = b2[1];
    const float* hp = hh + (size_t)s * 128;
    for (int k = 0; k < 128; ++k) {
        float v = hp[k];
        l0 += v * W2[k * 2];
        l1 += v * W2[k * 2 + 1];
    }
    float m = fmaxf(l0, l1);
    float e0 = __expf(l0 - m), e1 = __expf(l1 - m);
    float inv = 1.f / (e0 + e1);
    out[s * 2] = e0 * inv;
    out[s * 2 + 1] = e1 * inv;
}

extern "C" void kernel_launch(void* const* d_in, const int* in_sizes, int n_in,
                              void* d_out, int out_size, void* d_ws, size_t ws_size,
                              hipStream_t stream)
{
    (void)in_sizes; (void)n_in; (void)out_size; (void)ws_size;
    const float* T1 = (const float*)d_in[0];
    const float* T2 = (const float*)d_in[1];
    const float* Abias = (const float*)d_in[3];
    const float* convW_in = (const float*)d_in[4];
    const float* convB_in = (const float*)d_in[5];
    const float* convW = (const float*)d_in[6];
    const float* convB = (const float*)d_in[7];
    const float* fc0_W = (const float*)d_in[8];
    const float* fc0_b = (const float*)d_in[9];
    const float* fc_W = (const float*)d_in[10];
    const float* fc_b = (const float*)d_in[11];
    const float* pos = (const float*)d_in[12];
    const float* ln1_g = (const float*)d_in[13];
    const float* ln1_b = (const float*)d_in[14];
    const float* qkv_W = (const float*)d_in[15];
    const float* out_W = (const float*)d_in[16];
    const float* out_b = (const float*)d_in[17];
    const float* ln2_g = (const float*)d_in[18];
    const float* ln2_b = (const float*)d_in[19];
    const float* ff_W1 = (const float*)d_in[20];
    const float* ff_b1 = (const float*)d_in[21];
    const float* ff_W2 = (const float*)d_in[22];
    const float* ff_b2 = (const float*)d_in[23];
    const float* head_W1 = (const float*)d_in[24];
    const float* head_b1 = (const float*)d_in[25];
    const float* head_W2 = (const float*)d_in[26];
    const float* head_b2 = (const float*)d_in[27];
    float* outp = (float*)d_out;

    char* wp = (char*)d_ws;
    auto alloc = [&](size_t bytes) { char* p = wp; wp += (bytes + 255) & ~(size_t)255; return p; };
    short* cbufA = (short*)alloc(16777216);
    short* cbufB = (short*)alloc(16777216);
    short* wt0   = (short*)alloc(2064384);
    short* wtl   = (short*)alloc(11796480);
    short* zbuf  = (short*)alloc(256);
    short* thwc  = (short*)alloc(14680064);
    short* qkvWT = (short*)alloc(9437184);
    short* outWT = (short*)alloc(3145728);
    short* ff1T  = (short*)alloc(3145728);
    short* ff2T  = (short*)alloc(3145728);
    short* fcT   = (short*)alloc(2621440);
    short* fc0WT = (short*)alloc(245760);
    short* qkvb  = (short*)alloc(6291456);
    short* obuf  = (short*)alloc(2097152);
    short* hbuf  = (short*)alloc(1048576);
    short* h2b   = (short*)alloc(1048576);
    short* ffhb  = (short*)alloc(2097152);
    short* catr  = (short*)alloc(2097152);
    float* LSb    = (float*)alloc(1835008);
    float* xbuf   = (float*)alloc(2097152);
    float* hhb    = (float*)alloc(524288);

    auto gemm = [&](const short* A, long long sA, int lda, const short* Bt, long long sB,
                    int N, int K, float* Cf, long long sCf, short* Cb, long long sCb, int ldc,
                    const float* bias, long long sBias, const float* addm, long long sAdd, int ldadd, int act) {
        gemm64_k<<<dim3((unsigned)(N / 64), 16, 2), 256, 0, stream>>>(
            A, sA, lda, Bt, sB, K, Cf, sCf, Cb, sCb, ldc, bias, sBias, addm, sAdd, ldadd, act);
    };

    // ---- single mega-prep dispatch ----
    megaprep_k<<<68272, 256, 0, stream>>>(T1, T2, convW_in, convW, qkv_W, out_W, ff_W1, ff_W2,
                                          fc_W, fc0_W, wt0, wtl, zbuf, thwc, LSb,
                                          qkvWT, outWT, ff1T, ff2T, fcT, fc0WT);

    // conv layer 0 (224 -> 256)
    conv_mfma_k<<<512, 256, 0, stream>>>(thwc, 3670016LL, wt0, 516096LL, convB_in, 256LL,
                                         cbufA, 4194304LL, zbuf, 224);
    short* cur = cbufA; short* nxt = cbufB;
    for (int s = 0; s < 6; ++s) {
        if (s > 0) {
            conv_mfma_k<<<512, 256, 0, stream>>>(cur, 4194304LL, wtl + (size_t)(s - 1) * 2 * 589824,
                                                 589824LL, convB + (size_t)(s - 1) * 512, 256LL,
                                                 nxt, 4194304LL, zbuf, 256);
            short* t = cur; cur = nxt; nxt = t;
        }
        if (s == 0) {
            poolcat_k<<<dim3(1024, 2), 256, 0, stream>>>(cur, 4194304LL, LSb, 229376LL, 224, catr, 491520LL);
            gemm_ln_k<<<dim3(64, 2), 256, 0, stream>>>(
                catr, 491520LL, 480, fc0WT, 122880LL, 480, fc0_b, 256LL,
                pos, 262144LL, ln1_g, ln1_b, xbuf, 262144LL, hbuf, 262144LL);
        } else {
            poolcat_k<<<dim3(1024, 2), 256, 0, stream>>>(cur, 4194304LL, xbuf, 262144LL, 256, catr, 524288LL);
            gemm_ln_k<<<dim3(64, 2), 256, 0, stream>>>(
                catr, 524288LL, 512, fcT + (size_t)(s - 1) * 262144, 131072LL, 512,
                fc_b + (size_t)(s - 1) * 512, 256LL,
                pos + (size_t)s * 524288, 262144LL, ln1_g + s * 512, ln1_b + s * 512,
                xbuf, 262144LL, hbuf, 262144LL);
        }
        gemm(hbuf, 262144, 256, qkvWT + (size_t)s * 786432, 393216, 1536, 256,
             nullptr, 0, qkvb, 1572864, 1536, nullptr, 0, nullptr, 0, 0, 0);
        flash_k<<<dim3(16, 8, 2), 256, 0, stream>>>(qkvb, Abias, obuf);
        gemm_ln_k<<<dim3(64, 2), 256, 0, stream>>>(
            obuf, 524288LL, 512, outWT + (size_t)s * 262144, 131072LL, 512,
            out_b + s * 512, 256LL, xbuf, 262144LL, ln2_g + s * 512, ln2_b + s * 512,
            xbuf, 262144LL, h2b, 262144LL);
        gemm(h2b, 262144, 256, ff1T + (size_t)s * 262144, 131072, 512, 256,
             nullptr, 0, ffhb, 524288, 512, ff_b1 + s * 1024, 512, nullptr, 0, 0, 2);
        gemm(ffhb, 524288, 512, ff2T + (size_t)s * 262144, 131072, 256, 512, xbuf, 262144,
             nullptr, 0, 256, ff_b2 + s * 512, 256, xbuf, 262144, 256, 0);
    }
    // head
    head1_k<<<dim3(2, 16), 256, 0, stream>>>(xbuf, xbuf + 262144, head_W1, hhb, head_b1);
    head2_k<<<4, 256, 0, stream>>>(hhb, head_W2, head_b2, outp);
}

// Round 7
// 1116.595 us; speedup vs baseline: 1.1729x; 1.1729x over previous
//
#include <hip/hip_runtime.h>
#include <hip/hip_bf16.h>
#include <math.h>

#define SPX 1024
#define HW 16384

typedef short short8 __attribute__((ext_vector_type(8)));
typedef short short4v __attribute__((ext_vector_type(4)));
typedef float f32x4 __attribute__((ext_vector_type(4)));

__device__ inline short f2bf(float v){ union{ __hip_bfloat16 h; short s; } u; u.h = __float2bfloat16(v); return u.s; }
__device__ inline float bf2f(short s){ union{ __hip_bfloat16 h; short t; } u; u.t = s; return __bfloat162float(u.h); }

#define GLL(gp, lp) __builtin_amdgcn_global_load_lds( \
    (const __attribute__((address_space(1))) void*)(gp), \
    (__attribute__((address_space(3))) void*)(lp), 16, 0, 0)

// ---------------- mega prep: conv weights, THWC (tiled transpose), LS pooling, weight transposes ----
__global__ __launch_bounds__(256) void megaprep_k(
    const float* __restrict__ T1, const float* __restrict__ T2,
    const float* __restrict__ cwin, const float* __restrict__ cw,
    const float* __restrict__ qkvW, const float* __restrict__ outW,
    const float* __restrict__ ff1W, const float* __restrict__ ff2W,
    const float* __restrict__ fcW, const float* __restrict__ fc0W,
    short* __restrict__ wt0, short* __restrict__ wtl, short* __restrict__ zbuf,
    short* __restrict__ thwc, float* __restrict__ LSb,
    short* __restrict__ qkvWT, short* __restrict__ outWT,
    short* __restrict__ ff1T, short* __restrict__ ff2T,
    short* __restrict__ fcT, short* __restrict__ fc0WT)
{
    __shared__ float tile[32][33];
    int bid = blockIdx.x;
    int tid = threadIdx.x;
    if (bid < 27072) {
        long long idx = (long long)bid * 256 + tid;
        if (idx < 64) zbuf[idx] = 0;
        const long long n0 = 2LL * 256 * 2016;
        if (idx < n0) {
            int br = (int)(idx / (256 * 2016)); int rem = (int)(idx % (256 * 2016));
            int co = rem / 2016; int k = rem % 2016;
            int tap = k / 224, ci = k % 224;
            wt0[idx] = f2bf(cwin[((size_t)(br * 256 + co) * 224 + ci) * 9 + tap]);
        } else {
            long long i2 = idx - n0;
            if (i2 < 10LL * 256 * 2304) {
                int l = (int)(i2 / (256 * 2304)); int rem = (int)(i2 % (256 * 2304));
                int co = rem / 2304; int k = rem % 2304;
                int tap = k / 256, ci = k % 256;
                wtl[i2] = f2bf(cw[((size_t)(l * 256 + co) * 256 + ci) * 9 + tap]);
            }
        }
        return;
    }
    bid -= 27072;
    if (bid < 7168) {
        // CHW fp32 -> HWC bf16, 32ch x 32px LDS tile (coalesced both sides)
        int br = bid / 3584, rem2 = bid % 3584;
        int p0 = (rem2 / 7) * 32, c0 = (rem2 % 7) * 32;
        const float* src = br ? T2 : T1;
        int r = tid >> 3, c4 = (tid & 7) * 4;
        float4 v = *(const float4*)(src + (size_t)(c0 + r) * HW + p0 + c4);
        tile[r][c4 + 0] = v.x; tile[r][c4 + 1] = v.y; tile[r][c4 + 2] = v.z; tile[r][c4 + 3] = v.w;
        __syncthreads();
        short4v o;
#pragma unroll
        for (int i = 0; i < 4; ++i) o[i] = f2bf(tile[c4 + i][r]);
        *(short4v*)(thwc + (size_t)br * 3670016 + (size_t)(p0 + r) * 224 + c0 + c4) = o;
        return;
    }
    bid -= 7168;
    if (bid < 1792) {
        int idx = bid * 256 + tid;
        int z = idx / 229376; int rem = idx % 229376;
        int c = rem >> 10, s = rem & 1023;
        const float* src = z ? T2 : T1;
        const float* p = src + (size_t)c * HW + s;
        float acc = 0.f;
#pragma unroll
        for (int j = 0; j < 16; ++j) acc += p[j * 1024];
        LSb[(size_t)z * 229376 + (size_t)s * 224 + c] = acc * (1.f / 16.f);
        return;
    }
    bid -= 1792;
    const float* src; short* dst; int K, N, nx;
    if (bid < 4608)                        { src = qkvW; dst = qkvWT; K = 256; N = 1536; nx = 48; }
    else { bid -= 4608; if (bid < 1536)    { src = outW; dst = outWT; K = 512; N = 256;  nx = 8; }
    else { bid -= 1536; if (bid < 1536)    { src = ff1W; dst = ff1T;  K = 256; N = 512;  nx = 16; }
    else { bid -= 1536; if (bid < 1536)    { src = ff2W; dst = ff2T;  K = 512; N = 256;  nx = 8; }
    else { bid -= 1536; if (bid < 1280)    { src = fcW;  dst = fcT;   K = 512; N = 256;  nx = 8; }
    else { bid -= 1280;                      src = fc0W; dst = fc0WT; K = 480; N = 256;  nx = 8; } } } } }
    int per = nx * (K >> 5);
    int b = bid / per, rem = bid % per;
    int n0 = (rem % nx) * 32, k0 = (rem / nx) * 32;
    const float* s = src + (size_t)b * K * N;
    short* d = dst + (size_t)b * K * N;
    int r = tid >> 3, c4 = (tid & 7) * 4;
    float4 v = *(const float4*)(s + (size_t)(k0 + r) * N + n0 + c4);
    tile[r][c4 + 0] = v.x; tile[r][c4 + 1] = v.y; tile[r][c4 + 2] = v.z; tile[r][c4 + 3] = v.w;
    __syncthreads();
    short4v o;
#pragma unroll
    for (int i = 0; i < 4; ++i) o[i] = f2bf(tile[c4 + i][r]);
    *(short4v*)(d + (size_t)(n0 + r) * K + k0 + c4) = o;
}

// ---------------- conv v3 (reverted, measured 53us): halo-A staging + B LDS double-buffer --------
__global__ __launch_bounds__(256) void conv_mfma_k(
    const short* __restrict__ inB, long long inStride,
    const short* __restrict__ wtB, long long wtStride,
    const float* __restrict__ biasB, long long biasStride,
    short* __restrict__ outB, long long outStride,
    const short* __restrict__ zbuf, int Cin)
{
    __shared__ short Ah[3 * 4160];    // 3 dy x 130 rows x 32 ci (rows 0/129 zero guards)
    __shared__ short Bs[2][4096];     // double-buffered 128 co x 32 ci
    int id = blockIdx.x;
    int x7 = id & 7, t = id >> 3;
    int br = x7 & 1;
    int y = (x7 >> 1) * 32 + (t >> 1);
    int co0 = (t & 1) * 128;
    const short* in = inB + (size_t)br * inStride;
    const short* wt = wtB + (size_t)br * wtStride;
    const float* bias = biasB + (size_t)br * biasStride;
    short* out = outB + (size_t)br * outStride;
    int tid = threadIdx.x;
    int lane = tid & 63, w = tid >> 6;
    int wm = w >> 1, wn = w & 1;
    int lrow = lane >> 2, lsub = (lane & 3) * 8;
    int Kw = 9 * Cin;
    if (tid < 96) {
        int dy = tid >> 5, ci = tid & 31;
        Ah[dy * 4160 + ci] = 0;
        Ah[dy * 4160 + 129 * 32 + ci] = 0;
    }
    f32x4 acc[4][4];
#pragma unroll
    for (int i = 0; i < 4; ++i)
#pragma unroll
        for (int j = 0; j < 4; ++j) acc[i][j] = (f32x4){0.f, 0.f, 0.f, 0.f};

    auto stageA = [&](int cc) {
        int c8 = cc * 32;
#pragma unroll
        for (int g = 0; g < 6; ++g) {
            int idg = g * 4 + w;
            int dy = idg >> 3, grp = idg & 7;
            int gy = y + dy - 1;
            const short* gp = ((unsigned)gy < 128u)
                ? in + ((size_t)(gy * 128 + grp * 16 + lrow) * Cin + c8 + lsub)
                : zbuf + lsub;
            GLL(gp, Ah + dy * 4160 + (1 + grp * 16) * 32);
        }
    };
    auto stageB = [&](int cc, int tap, int p) {
        int c8 = cc * 32;
#pragma unroll
        for (int s = 0; s < 2; ++s) {
            int r0 = (s * 4 + w) * 16;
            const short* gq = wt + ((size_t)(co0 + r0 + lrow) * Kw + tap * Cin + c8 + lsub);
            GLL(gq, Bs[p] + r0 * 32);
        }
    };

    stageA(0);
    stageB(0, 0, 0);
    __syncthreads();
    int NC = Cin >> 5;
    int pb = 0;
    int mrow = lane & 15, kg = (lane >> 4) * 8;
    for (int cc = 0; cc < NC; ++cc) {
#pragma unroll
        for (int tap = 0; tap < 9; ++tap) {
            if (tap < 8) stageB(cc, tap + 1, pb ^ 1);
            else if (cc + 1 < NC) stageB(cc + 1, 0, pb ^ 1);
            int ky = tap / 3, kx = tap % 3;
            const short* Ap = Ah + ky * 4160 + kx * 32;
            short8 af[4], bfr[4];
#pragma unroll
            for (int i = 0; i < 4; ++i)
                af[i] = *(const short8*)(Ap + (wm * 64 + i * 16 + mrow) * 32 + kg);
#pragma unroll
            for (int j = 0; j < 4; ++j)
                bfr[j] = *(const short8*)(Bs[pb] + (wn * 64 + j * 16 + mrow) * 32 + kg);
#pragma unroll
            for (int i = 0; i < 4; ++i)
#pragma unroll
                for (int j = 0; j < 4; ++j)
                    acc[i][j] = __builtin_amdgcn_mfma_f32_16x16x32_bf16(af[i], bfr[j], acc[i][j], 0, 0, 0);
            __syncthreads();
            pb ^= 1;
        }
        if (cc + 1 < NC) {
            stageA(cc + 1);
            __syncthreads();
        }
    }
    int ln15 = lane & 15, quad = lane >> 4;
    float bj[4];
#pragma unroll
    for (int j = 0; j < 4; ++j) bj[j] = bias[co0 + wn * 64 + j * 16 + ln15];
#pragma unroll
    for (int i = 0; i < 4; ++i) {
#pragma unroll
        for (int r = 0; r < 4; ++r) {
            int px = wm * 64 + i * 16 + quad * 4 + r;
            size_t po = ((size_t)y * 128 + px) * 256 + co0 + wn * 64 + ln15;
#pragma unroll
            for (int j = 0; j < 4; ++j)
                out[po + j * 16] = f2bf(acc[i][j][r] + bj[j]);
        }
    }
}

// ---------------- bf16 MFMA GEMM, 64x64 tile, BK=32, double-buffered ----------------
__global__ __launch_bounds__(256) void gemm64_k(
    const short* __restrict__ A, long long sA, int lda,
    const short* __restrict__ Bt, long long sB, int K,
    float* Cf, long long sCf, short* Cb, long long sCb, int ldc,
    const float* __restrict__ bias, long long sBias,
    const float* addm, long long sAdd, int ldadd, int act)
{
    __shared__ short Asm[2][2048];
    __shared__ short Bsm[2][2048];
    int z = blockIdx.z;
    const short* Ap = A + (size_t)z * sA;
    const short* Bp = Bt + (size_t)z * sB;
    const float* biasp = bias ? bias + (size_t)z * sBias : nullptr;
    const float* addp = addm ? addm + (size_t)z * sAdd : nullptr;
    int bn = blockIdx.x * 64, bm = blockIdx.y * 64;
    int tid = threadIdx.x;
    int lane = tid & 63, w = tid >> 6;
    int wm = w >> 1, wn = w & 1;
    int rr = tid >> 2, lsub = (tid & 3) * 8;
    f32x4 acc[2][2];
#pragma unroll
    for (int i = 0; i < 2; ++i)
#pragma unroll
        for (int j = 0; j < 2; ++j) acc[i][j] = (f32x4){0.f, 0.f, 0.f, 0.f};

    auto stage = [&](int k0, int p) {
        GLL(Ap + (size_t)(bm + rr) * lda + k0 + lsub, Asm[p] + (w * 16) * 32);
        GLL(Bp + (size_t)(bn + rr) * K + k0 + lsub, Bsm[p] + (w * 16) * 32);
    };
    stage(0, 0);
    __syncthreads();
    int p = 0;
    int mrow = lane & 15, kg = (lane >> 4) * 8;
    for (int k0 = 0; k0 < K; k0 += 32) {
        if (k0 + 32 < K) stage(k0 + 32, p ^ 1);
        short8 af[2], bfr[2];
#pragma unroll
        for (int i = 0; i < 2; ++i)
            af[i] = *(const short8*)(Asm[p] + (wm * 32 + i * 16 + mrow) * 32 + kg);
#pragma unroll
        for (int j = 0; j < 2; ++j)
            bfr[j] = *(const short8*)(Bsm[p] + (wn * 32 + j * 16 + mrow) * 32 + kg);
#pragma unroll
        for (int i = 0; i < 2; ++i)
#pragma unroll
            for (int j = 0; j < 2; ++j)
                acc[i][j] = __builtin_amdgcn_mfma_f32_16x16x32_bf16(af[i], bfr[j], acc[i][j], 0, 0, 0);
        __syncthreads();
        p ^= 1;
    }
    int ln15 = lane & 15, quad = lane >> 4;
    float* Cfp = Cf ? Cf + (size_t)z * sCf : nullptr;
    short* Cbp = Cb ? Cb + (size_t)z * sCb : nullptr;
#pragma unroll
    for (int i = 0; i < 2; ++i) {
#pragma unroll
        for (int r = 0; r < 4; ++r) {
            int row = bm + wm * 32 + i * 16 + quad * 4 + r;
            long long ro = (long long)row * ldc;
#pragma unroll
            for (int j = 0; j < 2; ++j) {
                int col = bn + wn * 32 + j * 16 + ln15;
                float v = acc[i][j][r];
                if (biasp) v += biasp[col];
                if (addp) v += addp[(long long)row * ldadd + col];
                if (act == 1) v = fmaxf(v, 0.f);
                else if (act == 2) v = 0.5f * v * (1.f + erff(v * 0.70710678118f));
                if (Cfp) Cfp[ro + col] = v;
                if (Cbp) Cbp[ro + col] = f2bf(v);
            }
        }
    }
}

// ---------------- full-row GEMM (N=256) + bias + add + LayerNorm fused epilogue ----------------
__global__ __launch_bounds__(256) void gemm_ln_k(
    const short* __restrict__ A, long long sA, int lda,
    const short* __restrict__ Bt, long long sB, int K,
    const float* __restrict__ bias, long long sBias,
    const float* __restrict__ addm, long long sAdd,
    const float* __restrict__ g, const float* __restrict__ b,
    float* __restrict__ xout, long long sX, short* __restrict__ hout, long long sH)
{
    __shared__ short As[2][512];
    __shared__ short Bsm[2][8192];
    __shared__ float redS[16][4], redQ[16][4];
    int z = blockIdx.y;
    int bm = blockIdx.x * 16;
    const short* Ap = A + (size_t)z * sA;
    const short* Bp = Bt + (size_t)z * sB;
    const float* biasp = bias + (size_t)z * sBias;
    const float* addp = addm + (size_t)z * sAdd;
    const float* gp = g + (size_t)z * 256;
    const float* bp = b + (size_t)z * 256;
    float* xo = xout + (size_t)z * sX;
    short* ho = hout + (size_t)z * sH;
    int tid = threadIdx.x;
    int lane = tid & 63, w = tid >> 6;
    int lrow = lane >> 2, lsub = (lane & 3) * 8;
    int mrow = lane & 15, quad = lane >> 4, kg = quad * 8;
    f32x4 acc[4];
#pragma unroll
    for (int j = 0; j < 4; ++j) acc[j] = (f32x4){0.f, 0.f, 0.f, 0.f};

    auto stage = [&](int k0, int p) {
        if (w == 0) GLL(Ap + (size_t)(bm + lrow) * lda + k0 + lsub, As[p]);
#pragma unroll
        for (int s = 0; s < 4; ++s) {
            int r0 = (w * 4 + s) * 16;
            GLL(Bp + (size_t)(r0 + lrow) * K + k0 + lsub, Bsm[p] + r0 * 32);
        }
    };
    stage(0, 0);
    __syncthreads();
    int NK = K >> 5, p = 0;
    for (int kk = 0; kk < NK; ++kk) {
        if (kk + 1 < NK) stage((kk + 1) * 32, p ^ 1);
        short8 af = *(const short8*)(As[p] + mrow * 32 + kg);
#pragma unroll
        for (int j = 0; j < 4; ++j) {
            short8 bfr = *(const short8*)(Bsm[p] + (w * 64 + j * 16 + mrow) * 32 + kg);
            acc[j] = __builtin_amdgcn_mfma_f32_16x16x32_bf16(af, bfr, acc[j], 0, 0, 0);
        }
        __syncthreads();
        p ^= 1;
    }
    float v[4][4], s4[4], q4[4];
#pragma unroll
    for (int r = 0; r < 4; ++r) { s4[r] = 0.f; q4[r] = 0.f; }
#pragma unroll
    for (int j = 0; j < 4; ++j) {
        int col = w * 64 + j * 16 + mrow;
        float bb = biasp[col];
#pragma unroll
        for (int r = 0; r < 4; ++r) {
            int row = bm + quad * 4 + r;
            float val = acc[j][r] + bb + addp[(size_t)row * 256 + col];
            v[j][r] = val;
            s4[r] += val;
            q4[r] += val * val;
        }
    }
#pragma unroll
    for (int r = 0; r < 4; ++r) {
#pragma unroll
        for (int msk = 1; msk < 16; msk <<= 1) {
            s4[r] += __shfl_xor(s4[r], msk);
            q4[r] += __shfl_xor(q4[r], msk);
        }
    }
    if (mrow == 0) {
#pragma unroll
        for (int r = 0; r < 4; ++r) {
            redS[quad * 4 + r][w] = s4[r];
            redQ[quad * 4 + r][w] = q4[r];
        }
    }
    __syncthreads();
#pragma unroll
    for (int r = 0; r < 4; ++r) {
        int r16 = quad * 4 + r;
        float S = redS[r16][0] + redS[r16][1] + redS[r16][2] + redS[r16][3];
        float Q = redQ[r16][0] + redQ[r16][1] + redQ[r16][2] + redQ[r16][3];
        float m = S * (1.f / 256.f);
        float var = Q * (1.f / 256.f) - m * m;
        float rs = rsqrtf(var + 1e-5f);
        size_t ro = (size_t)(bm + r16) * 256;
#pragma unroll
        for (int j = 0; j < 4; ++j) {
            int col = w * 64 + j * 16 + mrow;
            xo[ro + col] = v[j][r];
            ho[ro + col] = f2bf((v[j][r] - m) * rs * gp[col] + bp[col]);
        }
    }
}

// ---------------- fused flash attention: per block (64 Q-rows, head, branch) ----------------
__global__ __launch_bounds__(256) void flash_k(const short* __restrict__ qkv, const float* __restrict__ Abias,
                                               short* __restrict__ obuf)
{
    __shared__ short Qs[64 * 72];
    __shared__ short Ks[128 * 72];
    __shared__ short Vt[64 * 136];
    __shared__ short Ps[64 * 136];
    int q0 = blockIdx.x * 64, h = blockIdx.y, br = blockIdx.z;
    const short* qb = qkv + (size_t)br * 1572864;
    int tid = threadIdx.x;
    int lane = tid & 63, w = tid >> 6;
    int ln15 = lane & 15, quad = lane >> 4;
    {
        int row = tid & 63, c0 = (tid >> 6) * 16;
        const short* src = qb + (size_t)(q0 + row) * 1536 + h * 64 + c0;
        *(short8*)(Qs + row * 72 + c0) = *(const short8*)src;
        *(short8*)(Qs + row * 72 + c0 + 8) = *(const short8*)(src + 8);
    }
    f32x4 Oc[4];
    float mrow[4], lsum[4];
#pragma unroll
    for (int i = 0; i < 4; ++i) { Oc[i] = (f32x4){0.f, 0.f, 0.f, 0.f}; mrow[i] = -1e30f; lsum[i] = 0.f; }

    for (int j = 0; j < 8; ++j) {
        int k0 = j * 128;
        {
            int row = tid & 127, half = tid >> 7;
            const short* ks = qb + (size_t)(k0 + row) * 1536 + 512 + h * 64 + half * 32;
#pragma unroll
            for (int g = 0; g < 4; ++g)
                *(short8*)(Ks + row * 72 + half * 32 + g * 8) = *(const short8*)(ks + g * 8);
            const short* vs = qb + (size_t)(k0 + row) * 1536 + 1024 + h * 64 + half * 32;
#pragma unroll
            for (int g = 0; g < 4; ++g) {
                short8 vv = *(const short8*)(vs + g * 8);
#pragma unroll
                for (int e = 0; e < 8; ++e)
                    Vt[(half * 32 + g * 8 + e) * 136 + row] = vv[e];
            }
        }
        __syncthreads();
        short8 aq[2];
#pragma unroll
        for (int g = 0; g < 2; ++g)
            aq[g] = *(const short8*)(Qs + (w * 16 + ln15) * 72 + g * 32 + quad * 8);
        f32x4 Sf[8];
#pragma unroll
        for (int nf = 0; nf < 8; ++nf) Sf[nf] = (f32x4){0.f, 0.f, 0.f, 0.f};
#pragma unroll
        for (int nf = 0; nf < 8; ++nf)
#pragma unroll
            for (int g = 0; g < 2; ++g) {
                short8 bk = *(const short8*)(Ks + (nf * 16 + ln15) * 72 + g * 32 + quad * 8);
                Sf[nf] = __builtin_amdgcn_mfma_f32_16x16x32_bf16(aq[g], bk, Sf[nf], 0, 0, 0);
            }
        float rm[4] = {-1e30f, -1e30f, -1e30f, -1e30f};
#pragma unroll
        for (int nf = 0; nf < 8; ++nf)
#pragma unroll
            for (int r = 0; r < 4; ++r) {
                float v = Sf[nf][r] * 0.125f +
                          Abias[(size_t)(q0 + w * 16 + quad * 4 + r) * 1024 + k0 + nf * 16 + ln15];
                Sf[nf][r] = v;
                rm[r] = fmaxf(rm[r], v);
            }
#pragma unroll
        for (int r = 0; r < 4; ++r)
#pragma unroll
            for (int msk = 1; msk < 16; msk <<= 1)
                rm[r] = fmaxf(rm[r], __shfl_xor(rm[r], msk));
        float alpha[4], rs[4];
#pragma unroll
        for (int r = 0; r < 4; ++r) {
            float mnew = fmaxf(mrow[r], rm[r]);
            alpha[r] = __expf(mrow[r] - mnew);
            mrow[r] = mnew;
            rs[r] = 0.f;
        }
#pragma unroll
        for (int nf = 0; nf < 8; ++nf)
#pragma unroll
            for (int r = 0; r < 4; ++r) {
                float pv = __expf(Sf[nf][r] - mrow[r]);
                Sf[nf][r] = pv;
                rs[r] += pv;
            }
#pragma unroll
        for (int r = 0; r < 4; ++r) {
#pragma unroll
            for (int msk = 1; msk < 16; msk <<= 1)
                rs[r] += __shfl_xor(rs[r], msk);
            lsum[r] = lsum[r] * alpha[r] + rs[r];
        }
#pragma unroll
        for (int nf = 0; nf < 4; ++nf)
#pragma unroll
            for (int r = 0; r < 4; ++r) Oc[nf][r] *= alpha[r];
#pragma unroll
        for (int nf = 0; nf < 8; ++nf)
#pragma unroll
            for (int r = 0; r < 4; ++r)
                Ps[(w * 16 + quad * 4 + r) * 136 + nf * 16 + ln15] = f2bf(Sf[nf][r]);
        __syncthreads();
#pragma unroll
        for (int g = 0; g < 4; ++g) {
            short8 ap = *(const short8*)(Ps + (w * 16 + ln15) * 136 + g * 32 + quad * 8);
#pragma unroll
            for (int nf = 0; nf < 4; ++nf) {
                short8 bv = *(const short8*)(Vt + (nf * 16 + ln15) * 136 + g * 32 + quad * 8);
                Oc[nf] = __builtin_amdgcn_mfma_f32_16x16x32_bf16(ap, bv, Oc[nf], 0, 0, 0);
            }
        }
        __syncthreads();
    }
#pragma unroll
    for (int nf = 0; nf < 4; ++nf)
#pragma unroll
        for (int r = 0; r < 4; ++r) {
            int row = q0 + w * 16 + quad * 4 + r;
            obuf[(size_t)br * 524288 + (size_t)row * 512 + h * 64 + nf * 16 + ln15] =
                f2bf(Oc[nf][r] / lsum[r]);
        }
}

// ---------------- fused pool(conv,256) + concat(b,cb) + relu -> bf16 catr ----------------
__global__ __launch_bounds__(256) void poolcat_k(const short* __restrict__ conv, long long convZ,
                                                 const float* __restrict__ bsrc, long long bZ, int cb,
                                                 short* __restrict__ catr, long long catZ)
{
    int row = blockIdx.x, z = blockIdx.y, tid = threadIdx.x;
    const short* p = conv + (size_t)z * convZ + (size_t)row * 256 + tid;
    float acc = 0.f;
#pragma unroll
    for (int j = 0; j < 16; ++j) acc += bf2f(p[(size_t)j * 262144]);
    int n = 256 + cb;
    short* op = catr + (size_t)z * catZ + (size_t)row * n;
    op[tid] = f2bf(fmaxf(acc * (1.f / 16.f), 0.f));
    if (tid < cb)
        op[256 + tid] = f2bf(fmaxf(bsrc[(size_t)z * bZ + (size_t)row * cb + tid], 0.f));
}

// ---------------- head GEMM with fused |x0-x1| A-staging (fp32, 64x64 tiles) ----------------
__global__ __launch_bounds__(256) void head1_k(const float* __restrict__ x0, const float* __restrict__ x1,
                                               const float* __restrict__ B, float* __restrict__ C,
                                               const float* __restrict__ bias)
{
    __shared__ __align__(16) float As[16][68];
    __shared__ __align__(16) float Bs[16][68];
    const int K = 256, lda = 256, ldb = 128, ldc = 128;
    int bn = blockIdx.x * 64, bm = blockIdx.y * 64;
    int tid = threadIdx.x;
    int tx = tid & 15, ty = tid >> 4;
    float acc[4][4];
#pragma unroll
    for (int r = 0; r < 4; ++r)
#pragma unroll
        for (int c = 0; c < 4; ++c) acc[r][c] = 0.f;
    int mmA = tid >> 2, kqA = (tid & 3) * 4;
    int kkB = tid >> 4, nqB = (tid & 15) * 4;
    for (int k0 = 0; k0 < K; k0 += 16) {
        float4 a0 = *(const float4*)(x0 + (long long)(bm + mmA) * lda + k0 + kqA);
        float4 a1 = *(const float4*)(x1 + (long long)(bm + mmA) * lda + k0 + kqA);
        As[kqA + 0][mmA] = fabsf(a0.x - a1.x); As[kqA + 1][mmA] = fabsf(a0.y - a1.y);
        As[kqA + 2][mmA] = fabsf(a0.z - a1.z); As[kqA + 3][mmA] = fabsf(a0.w - a1.w);
        *(float4*)&Bs[kkB][nqB] = *(const float4*)(B + (long long)(k0 + kkB) * ldb + bn + nqB);
        __syncthreads();
#pragma unroll
        for (int kk = 0; kk < 16; ++kk) {
            float4 a4 = *(const float4*)&As[kk][ty * 4];
            float4 b4 = *(const float4*)&Bs[kk][tx * 4];
            float ar[4] = {a4.x, a4.y, a4.z, a4.w};
            float br[4] = {b4.x, b4.y, b4.z, b4.w};
#pragma unroll
            for (int r = 0; r < 4; ++r)
#pragma unroll
                for (int c = 0; c < 4; ++c) acc[r][c] += ar[r] * br[c];
        }
        __syncthreads();
    }
#pragma unroll
    for (int r = 0; r < 4; ++r) {
        int row = bm + ty * 4 + r;
#pragma unroll
        for (int c = 0; c < 4; ++c) {
            int col = bn + tx * 4 + c;
            C[(long long)row * ldc + col] = fmaxf(acc[r][c] + bias[col], 0.f);
        }
    }
}

__global__ __launch_bounds__(256) void head2_k(const float* __restrict__ hh, const float* __restrict__ W2,
                                               const float* __restrict__ b2, float* __restrict__ out)
{
    int s = blockIdx.x * 256 + threadIdx.x;
    if (s >= SPX) return;
    float l0 = b2[0], l1 = b2[1];
    const float* hp = hh + (size_t)s * 128;
    for (int k = 0; k < 128; ++k) {
        float v = hp[k];
        l0 += v * W2[k * 2];
        l1 += v * W2[k * 2 + 1];
    }
    float m = fmaxf(l0, l1);
    float e0 = __expf(l0 - m), e1 = __expf(l1 - m);
    float inv = 1.f / (e0 + e1);
    out[s * 2] = e0 * inv;
    out[s * 2 + 1] = e1 * inv;
}

extern "C" void kernel_launch(void* const* d_in, const int* in_sizes, int n_in,
                              void* d_out, int out_size, void* d_ws, size_t ws_size,
                              hipStream_t stream)
{
    (void)in_sizes; (void)n_in; (void)out_size; (void)ws_size;
    const float* T1 = (const float*)d_in[0];
    const float* T2 = (const float*)d_in[1];
    const float* Abias = (const float*)d_in[3];
    const float* convW_in = (const float*)d_in[4];
    const float* convB_in = (const float*)d_in[5];
    const float* convW = (const float*)d_in[6];
    const float* convB = (const float*)d_in[7];
    const float* fc0_W = (const float*)d_in[8];
    const float* fc0_b = (const float*)d_in[9];
    const float* fc_W = (const float*)d_in[10];
    const float* fc_b = (const float*)d_in[11];
    const float* pos = (const float*)d_in[12];
    const float* ln1_g = (const float*)d_in[13];
    const float* ln1_b = (const float*)d_in[14];
    const float* qkv_W = (const float*)d_in[15];
    const float* out_W = (const float*)d_in[16];
    const float* out_b = (const float*)d_in[17];
    const float* ln2_g = (const float*)d_in[18];
    const float* ln2_b = (const float*)d_in[19];
    const float* ff_W1 = (const float*)d_in[20];
    const float* ff_b1 = (const float*)d_in[21];
    const float* ff_W2 = (const float*)d_in[22];
    const float* ff_b2 = (const float*)d_in[23];
    const float* head_W1 = (const float*)d_in[24];
    const float* head_b1 = (const float*)d_in[25];
    const float* head_W2 = (const float*)d_in[26];
    const float* head_b2 = (const float*)d_in[27];
    float* outp = (float*)d_out;

    char* wp = (char*)d_ws;
    auto alloc = [&](size_t bytes) { char* p = wp; wp += (bytes + 255) & ~(size_t)255; return p; };
    short* cbufA = (short*)alloc(16777216);
    short* cbufB = (short*)alloc(16777216);
    short* wt0   = (short*)alloc(2064384);
    short* wtl   = (short*)alloc(11796480);
    short* zbuf  = (short*)alloc(256);
    short* thwc  = (short*)alloc(14680064);
    short* qkvWT = (short*)alloc(9437184);
    short* outWT = (short*)alloc(3145728);
    short* ff1T  = (short*)alloc(3145728);
    short* ff2T  = (short*)alloc(3145728);
    short* fcT   = (short*)alloc(2621440);
    short* fc0WT = (short*)alloc(245760);
    short* qkvb  = (short*)alloc(6291456);
    short* obuf  = (short*)alloc(2097152);
    short* hbuf  = (short*)alloc(1048576);
    short* h2b   = (short*)alloc(1048576);
    short* ffhb  = (short*)alloc(2097152);
    short* catr  = (short*)alloc(2097152);
    float* LSb    = (float*)alloc(1835008);
    float* xbuf   = (float*)alloc(2097152);
    float* hhb    = (float*)alloc(524288);

    auto gemm = [&](const short* A, long long sA, int lda, const short* Bt, long long sB,
                    int N, int K, float* Cf, long long sCf, short* Cb, long long sCb, int ldc,
                    const float* bias, long long sBias, const float* addm, long long sAdd, int ldadd, int act) {
        gemm64_k<<<dim3((unsigned)(N / 64), 16, 2), 256, 0, stream>>>(
            A, sA, lda, Bt, sB, K, Cf, sCf, Cb, sCb, ldc, bias, sBias, addm, sAdd, ldadd, act);
    };

    // ---- single mega-prep dispatch (46768 blocks) ----
    megaprep_k<<<46768, 256, 0, stream>>>(T1, T2, convW_in, convW, qkv_W, out_W, ff_W1, ff_W2,
                                          fc_W, fc0_W, wt0, wtl, zbuf, thwc, LSb,
                                          qkvWT, outWT, ff1T, ff2T, fcT, fc0WT);

    // conv layer 0 (224 -> 256)
    conv_mfma_k<<<512, 256, 0, stream>>>(thwc, 3670016LL, wt0, 516096LL, convB_in, 256LL,
                                         cbufA, 4194304LL, zbuf, 224);
    short* cur = cbufA; short* nxt = cbufB;
    for (int s = 0; s < 6; ++s) {
        if (s > 0) {
            conv_mfma_k<<<512, 256, 0, stream>>>(cur, 4194304LL, wtl + (size_t)(s - 1) * 2 * 589824,
                                                 589824LL, convB + (size_t)(s - 1) * 512, 256LL,
                                                 nxt, 4194304LL, zbuf, 256);
            short* t = cur; cur = nxt; nxt = t;
        }
        if (s == 0) {
            poolcat_k<<<dim3(1024, 2), 256, 0, stream>>>(cur, 4194304LL, LSb, 229376LL, 224, catr, 491520LL);
            gemm_ln_k<<<dim3(64, 2), 256, 0, stream>>>(
                catr, 491520LL, 480, fc0WT, 122880LL, 480, fc0_b, 256LL,
                pos, 262144LL, ln1_g, ln1_b, xbuf, 262144LL, hbuf, 262144LL);
        } else {
            poolcat_k<<<dim3(1024, 2), 256, 0, stream>>>(cur, 4194304LL, xbuf, 262144LL, 256, catr, 524288LL);
            gemm_ln_k<<<dim3(64, 2), 256, 0, stream>>>(
                catr, 524288LL, 512, fcT + (size_t)(s - 1) * 262144, 131072LL, 512,
                fc_b + (size_t)(s - 1) * 512, 256LL,
                pos + (size_t)s * 524288, 262144LL, ln1_g + s * 512, ln1_b + s * 512,
                xbuf, 262144LL, hbuf, 262144LL);
        }
        gemm(hbuf, 262144, 256, qkvWT + (size_t)s * 786432, 393216, 1536, 256,
             nullptr, 0, qkvb, 1572864, 1536, nullptr, 0, nullptr, 0, 0, 0);
        flash_k<<<dim3(16, 8, 2), 256, 0, stream>>>(qkvb, Abias, obuf);
        gemm_ln_k<<<dim3(64, 2), 256, 0, stream>>>(
            obuf, 524288LL, 512, outWT + (size_t)s * 262144, 131072LL, 512,
            out_b + s * 512, 256LL, xbuf, 262144LL, ln2_g + s * 512, ln2_b + s * 512,
            xbuf, 262144LL, h2b, 262144LL);
        gemm(h2b, 262144, 256, ff1T + (size_t)s * 262144, 131072, 512, 256,
             nullptr, 0, ffhb, 524288, 512, ff_b1 + s * 1024, 512, nullptr, 0, 0, 2);
        gemm(ffhb, 524288, 512, ff2T + (size_t)s * 262144, 131072, 256, 512, xbuf, 262144,
             nullptr, 0, 256, ff_b2 + s * 512, 256, xbuf, 262144, 256, 0);
    }
    // head
    head1_k<<<dim3(2, 16), 256, 0, stream>>>(xbuf, xbuf + 262144, head_W1, hhb, head_b1);
    head2_k<<<4, 256, 0, stream>>>(hhb, head_W2, head_b2, outp);
}